// Round 10
// baseline (1623.004 us; speedup 1.0000x reference)
//
#include <hip/hip_runtime.h>
#include <hip/hip_bf16.h>
#include <hip/hip_fp16.h>

// 2-layer GCN, N=100000 nodes, E=3.2M edges, dims 128 -> 64 -> 2, fp32.
// R10: csw/rp/k_build ELIMINATED. Aggregation consumes bucket-sorted ebuf
// directly: one block per 128-node bucket, LDS fp32 accumulator
// acc[128][64] via ds_add_f32 (conflict-free: 64 lanes -> 64 banks).
// k_deg computes dinv from ebuf; k_agg2 fuses agg+bias+ReLU+W2;
// k_prop3 does layer-2 with acc[128][2]. 9 kernels total.

#define DIN  128
#define DHID 64
#define BSH  7                    // bucket shift: 128 nodes/bucket

typedef _Float16 half8 __attribute__((ext_vector_type(8)));
typedef float    f32x4 __attribute__((ext_vector_type(4)));

// ---------------- K1: per-chunk coarse histogram (LDS only) --------
__global__ __launch_bounds__(256) void k_hist(const int* __restrict__ ei,
                                              int* __restrict__ histT,
                                              int E, int chunk, int B, int C) {
    extern __shared__ int h[];
    for (int t = threadIdx.x; t < B; t += 256) h[t] = 0;
    __syncthreads();
    int c = blockIdx.x;
    int e0 = c * chunk, e1 = min(E, e0 + chunk);
    for (int e = e0 + threadIdx.x; e < e1; e += 256)
        atomicAdd(&h[ei[E + e] >> BSH], 1);
    __syncthreads();
    for (int t = threadIdx.x; t < B; t += 256) histT[(size_t)t * C + c] = h[t];
}

// ------- K2: per-bucket exclusive scan over its 256 chunk-cells ----
__global__ __launch_bounds__(256) void k_scan1(int* __restrict__ histT,
                                               int* __restrict__ tot, int C) {
    __shared__ int sm[256];
    int b = blockIdx.x, t = threadIdx.x;
    size_t base = (size_t)b * C;
    int v = histT[base + t];
    sm[t] = v;
    __syncthreads();
    for (int off = 1; off < 256; off <<= 1) {
        int add = (t >= off) ? sm[t - off] : 0;
        __syncthreads();
        sm[t] += add;
        __syncthreads();
    }
    histT[base + t] = sm[t] - v;          // exclusive within bucket
    if (t == 255) tot[b] = sm[t];
}

// ------- K3: exclusive scan of bucket totals -> bucket bases -------
__global__ __launch_bounds__(1024) void k_scan2(const int* __restrict__ tot,
                                                int* __restrict__ bb, int B) {
    __shared__ int sm[1024];
    int t = threadIdx.x;
    int v = (t < B) ? tot[t] : 0;
    sm[t] = v;
    __syncthreads();
    for (int off = 1; off < 1024; off <<= 1) {
        int add = (t >= off) ? sm[t - off] : 0;
        __syncthreads();
        sm[t] += add;
        __syncthreads();
    }
    if (t < B) {
        bb[t] = sm[t] - v;
        if (t == B - 1) bb[B] = sm[t];
    }
}

// ---------------- K4: scatter edges into bucket-sorted ebuf --------
// ebuf entry: {(local_node << 24) | src, w_bits}; cell-contiguous writes.
__global__ __launch_bounds__(256) void k_scatter(const int* __restrict__ ei,
                                                 const float* __restrict__ ew,
                                                 const int* __restrict__ histT,
                                                 const int* __restrict__ bb,
                                                 int2* __restrict__ ebuf,
                                                 int E, int chunk, int B, int C) {
    extern __shared__ int cur[];
    int c = blockIdx.x;
    for (int t = threadIdx.x; t < B; t += 256)
        cur[t] = histT[(size_t)t * C + c] + bb[t];
    __syncthreads();
    int e0 = c * chunk, e1 = min(E, e0 + chunk);
    for (int e = e0 + threadIdx.x; e < e1; e += 256) {
        int s = ei[e];
        int d = ei[E + e];
        float w = ew[e];
        int b = d >> BSH;
        int pos = atomicAdd(&cur[b], 1);   // LDS atomic
        ebuf[pos] = make_int2(s | ((d & 127) << 24), __float_as_int(w));
    }
}

// ---------------- K5: dinv from ebuf (per-bucket LDS sum) ----------
__global__ __launch_bounds__(256) void k_deg(const int2* __restrict__ ebuf,
                                             const int* __restrict__ bb,
                                             float* __restrict__ dinv, int N) {
    __shared__ float dsum[128];
    int b = blockIdx.x, t = threadIdx.x;
    if (t < 128) dsum[t] = 0.0f;
    __syncthreads();
    int p0 = bb[b], p1 = bb[b + 1];
    for (int p = p0 + t; p < p1; p += 256) {
        int2 v = ebuf[p];
        atomicAdd(&dsum[(((unsigned)v.x) >> 24) & 127], __int_as_float(v.y));
    }
    __syncthreads();
    if (t < 128) {
        int i = (b << BSH) + t;
        if (i < N) dinv[i] = rsqrtf(1.0f + dsum[t]);
    }
}

// ---------------- K6a: W1 -> fp16 (one block) ----------------------
__global__ __launch_bounds__(256) void k_w1h(const float* __restrict__ W1,
                                             __half* __restrict__ W1h) {
    for (int i = threadIdx.x; i < DIN * DHID; i += 256)
        W1h[i] = __float2half(W1[i]);
}

// ---------------- K6b: h1 = fp16(x @ W1) via MFMA ------------------
__global__ __launch_bounds__(256) void k_gemm1(const float* __restrict__ x,
                                               const __half* __restrict__ W1h,
                                               __half* __restrict__ h1, int N) {
    __shared__ _Float16 As[64][136];
    __shared__ _Float16 Bs[64][136];   // Bs[col][k]
    int t = threadIdx.x;
    int wave = t >> 6, lane = t & 63;
    int r0 = blockIdx.x * 64;

    for (int idx = t; idx < DIN * DHID; idx += 256) {
        int k = idx >> 6, c = idx & 63;
        Bs[c][k] = (_Float16)__half2float(W1h[idx]);
    }
    const float4* xv = (const float4*)x;
    for (int idx = t; idx < 64 * 32; idx += 256) {
        int r = idx >> 5, c4 = idx & 31;
        int rr = r0 + r;
        float4 v = (rr < N) ? xv[(size_t)rr * 32 + c4]
                            : make_float4(0.f, 0.f, 0.f, 0.f);
        As[r][c4 * 4 + 0] = (_Float16)v.x;
        As[r][c4 * 4 + 1] = (_Float16)v.y;
        As[r][c4 * 4 + 2] = (_Float16)v.z;
        As[r][c4 * 4 + 3] = (_Float16)v.w;
    }
    __syncthreads();

    int row = lane & 15;
    int kg  = lane >> 4;
    f32x4 acc0 = {0.f,0.f,0.f,0.f}, acc1 = {0.f,0.f,0.f,0.f};
    f32x4 acc2 = {0.f,0.f,0.f,0.f}, acc3 = {0.f,0.f,0.f,0.f};
#pragma unroll
    for (int kc = 0; kc < 4; ++kc) {
        half8 a = *(const half8*)&As[wave * 16 + row][kc * 32 + kg * 8];
        half8 b0 = *(const half8*)&Bs[ 0 + row][kc * 32 + kg * 8];
        half8 b1 = *(const half8*)&Bs[16 + row][kc * 32 + kg * 8];
        half8 b2 = *(const half8*)&Bs[32 + row][kc * 32 + kg * 8];
        half8 b3 = *(const half8*)&Bs[48 + row][kc * 32 + kg * 8];
        acc0 = __builtin_amdgcn_mfma_f32_16x16x32_f16(a, b0, acc0, 0, 0, 0);
        acc1 = __builtin_amdgcn_mfma_f32_16x16x32_f16(a, b1, acc1, 0, 0, 0);
        acc2 = __builtin_amdgcn_mfma_f32_16x16x32_f16(a, b2, acc2, 0, 0, 0);
        acc3 = __builtin_amdgcn_mfma_f32_16x16x32_f16(a, b3, acc3, 0, 0, 0);
    }
#pragma unroll
    for (int reg = 0; reg < 4; ++reg) {
        int rr = r0 + wave * 16 + kg * 4 + reg;
        if (rr < N) {
            int col = lane & 15;
            size_t base = (size_t)rr * DHID;
            h1[base + col +  0] = __float2half(acc0[reg]);
            h1[base + col + 16] = __float2half(acc1[reg]);
            h1[base + col + 32] = __float2half(acc2[reg]);
            h1[base + col + 48] = __float2half(acc3[reg]);
        }
    }
}

// ------- K7: layer-1 aggregate + bias + ReLU + @W2, per bucket -----
// acc[128][64] fp32 in LDS; waves stream edges wave-uniformly (unroll 8);
// ds_add_f32 per lane (64 consecutive banks = conflict-free).
__global__ __launch_bounds__(256) void k_agg2(const __half* __restrict__ h1h,
                                              const int2* __restrict__ ebuf,
                                              const int* __restrict__ bb,
                                              const float* __restrict__ dinv,
                                              const float* __restrict__ b1,
                                              const float* __restrict__ W2,
                                              float* __restrict__ h2, int N) {
    __shared__ float acc[128][DHID];   // 32 KB
    int b = blockIdx.x, t = threadIdx.x;
    int wave = t >> 6, lane = t & 63;
    for (int q = t; q < 128 * DHID; q += 256) ((float*)acc)[q] = 0.0f;
    __syncthreads();

    int p0 = bb[b], p1 = bb[b + 1];

#define EDGE1(P)                                                           \
    {                                                                      \
        int2 ev = ebuf[P];                                                 \
        int vx = __builtin_amdgcn_readfirstlane(ev.x);                     \
        float wv = __uint_as_float(__builtin_amdgcn_readfirstlane(ev.y));  \
        int src = vx & 0xFFFFFF;                                           \
        int ln = (((unsigned)vx) >> 24) & 127;                             \
        float wn = wv * dinv[src];                                         \
        float hv = __half2float(h1h[(size_t)src * DHID + lane]);           \
        atomicAdd(&acc[ln][lane], wn * hv);                                \
    }

    int p = p0 + wave;                 // wave-interleaved, stride 4
    for (; p + 28 < p1; p += 32) {     // 8 edges per wave per iter
        EDGE1(p);       EDGE1(p + 4);  EDGE1(p + 8);  EDGE1(p + 12);
        EDGE1(p + 16);  EDGE1(p + 20); EDGE1(p + 24); EDGE1(p + 28);
    }
    for (; p < p1; p += 4) EDGE1(p);
#undef EDGE1
    __syncthreads();

    // epilogue: 4 waves x 32 nodes
    float bias = b1[lane];
    float w2a = W2[lane * 2];
    float w2b = W2[lane * 2 + 1];
    for (int k = 0; k < 32; ++k) {
        int ln = wave * 32 + k;
        int i = (b << BSH) + ln;
        if (i >= N) break;
        float di = dinv[i];
        float self = __half2float(h1h[(size_t)i * DHID + lane]);
        float a = (acc[ln][lane] + di * self) * di;
        a = fmaxf(a + bias, 0.0f);
        float o0 = a * w2a, o1 = a * w2b;
        for (int off = 32; off > 0; off >>= 1) {
            o0 += __shfl_xor(o0, off);
            o1 += __shfl_xor(o1, off);
        }
        if (lane == 0) {
            h2[i * 2]     = o0;
            h2[i * 2 + 1] = o1;
        }
    }
}

// ------- K8: layer-2 propagate per bucket: acc[128][2] in LDS ------
__global__ __launch_bounds__(256) void k_prop3(const float* __restrict__ h2,
                                               const int2* __restrict__ ebuf,
                                               const int* __restrict__ bb,
                                               const float* __restrict__ dinv,
                                               const float* __restrict__ b2,
                                               float* __restrict__ out, int N) {
    __shared__ float acc[128][2];
    const float2* h2v = (const float2*)h2;
    int b = blockIdx.x, t = threadIdx.x;
    if (t < 256) { if (t < 128) { acc[t][0] = 0.0f; acc[t][1] = 0.0f; } }
    __syncthreads();
    int p0 = bb[b], p1 = bb[b + 1];
    for (int p = p0 + t; p < p1; p += 256) {
        int2 v = ebuf[p];
        int src = v.x & 0xFFFFFF;
        int ln = (((unsigned)v.x) >> 24) & 127;
        float wn = __int_as_float(v.y) * dinv[src];
        float2 hv = h2v[src];
        atomicAdd(&acc[ln][0], wn * hv.x);
        atomicAdd(&acc[ln][1], wn * hv.y);
    }
    __syncthreads();
    if (t < 128) {
        int i = (b << BSH) + t;
        if (i < N) {
            float di = dinv[i];
            out[i * 2]     = di * (acc[t][0] + di * h2[i * 2])     + b2[0];
            out[i * 2 + 1] = di * (acc[t][1] + di * h2[i * 2 + 1]) + b2[1];
        }
    }
}

extern "C" void kernel_launch(void* const* d_in, const int* in_sizes, int n_in,
                              void* d_out, int out_size, void* d_ws, size_t ws_size,
                              hipStream_t stream) {
    const float* x  = (const float*)d_in[0];
    const int*   ei = (const int*)d_in[1];     // int32 per harness contract
    const float* ew = (const float*)d_in[2];
    const float* W1 = (const float*)d_in[3];
    const float* b1 = (const float*)d_in[4];
    const float* W2 = (const float*)d_in[5];
    const float* b2 = (const float*)d_in[6];
    float* out = (float*)d_out;

    const int N = in_sizes[0] / DIN;   // 100000
    const int E = in_sizes[2];         // 3200000

    const int C = 256;                 // edge chunks
    const int B = (N + 127) >> BSH;    // 782 buckets of 128 nodes
    const int chunk = (E + C - 1) / C;

    // workspace layout (~40.5 MB, no aliasing)
    char* w0 = (char*)d_ws;
    float* dinv  = (float*)w0;                      // N floats
    int*   histT = (int*)(dinv + N);                // B*C ints (800 KB)
    int*   tot   = histT + (size_t)B * C;           // B ints
    int*   bb    = tot + B;                         // B+1 ints
    size_t off_ebuf = ((size_t)((char*)(bb + B + 1) - w0) + 15) & ~(size_t)15;
    int2*  ebuf = (int2*)(w0 + off_ebuf);           // E pairs (25.6 MB)
    __half* h1  = (__half*)(ebuf + E);              // N*64 fp16 (12.8 MB)
    float* h2   = (float*)(h1 + (size_t)N * DHID);  // N*2 fp32
    __half* W1h = (__half*)(h2 + 2 * N);            // 8192 fp16 (16 KB)

    size_t ldsB = (size_t)B * sizeof(int);

    k_hist<<<C, 256, ldsB, stream>>>(ei, histT, E, chunk, B, C);
    k_scan1<<<B, 256, 0, stream>>>(histT, tot, C);
    k_scan2<<<1, 1024, 0, stream>>>(tot, bb, B);
    k_scatter<<<C, 256, ldsB, stream>>>(ei, ew, histT, bb, ebuf, E, chunk, B, C);
    k_deg<<<B, 256, 0, stream>>>(ebuf, bb, dinv, N);

    k_w1h<<<1, 256, 0, stream>>>(W1, W1h);
    const int GB = (N + 63) / 64;
    k_gemm1<<<GB, 256, 0, stream>>>(x, W1h, h1, N);

    k_agg2<<<B, 256, 0, stream>>>(h1, ebuf, bb, dinv, b1, W2, h2, N);
    k_prop3<<<B, 256, 0, stream>>>(h2, ebuf, bb, dinv, b2, out, N);
}

// Round 11
// 1621.425 us; speedup vs baseline: 1.0010x; 1.0010x over previous
//
#include <hip/hip_runtime.h>
#include <hip/hip_bf16.h>
#include <hip/hip_fp16.h>

// 2-layer GCN, N=100000 nodes, E=3.2M edges, dims 128 -> 64 -> 2, fp32.
// R11: R10's k_agg2 was a latency stall (12 waves/CU x ~1 outstanding gather;
// 127 GB/s, VALU 3.9%). Rewritten: 512-thread blocks (8 waves) + explicitly
// phased 8-edge batches (8 indep ebuf loads -> 8 dinv -> 8 gathers -> 8
// ds_add_f32). k_w1h folded into k_gemm1. Build-free pipeline kept.

#define DIN  128
#define DHID 64
#define BSH  7                    // bucket shift: 128 nodes/bucket

typedef _Float16 half8 __attribute__((ext_vector_type(8)));
typedef float    f32x4 __attribute__((ext_vector_type(4)));

// ---------------- K1: per-chunk coarse histogram (LDS only) --------
__global__ __launch_bounds__(256) void k_hist(const int* __restrict__ ei,
                                              int* __restrict__ histT,
                                              int E, int chunk, int B, int C) {
    extern __shared__ int h[];
    for (int t = threadIdx.x; t < B; t += 256) h[t] = 0;
    __syncthreads();
    int c = blockIdx.x;
    int e0 = c * chunk, e1 = min(E, e0 + chunk);
    for (int e = e0 + threadIdx.x; e < e1; e += 256)
        atomicAdd(&h[ei[E + e] >> BSH], 1);
    __syncthreads();
    for (int t = threadIdx.x; t < B; t += 256) histT[(size_t)t * C + c] = h[t];
}

// ------- K2: per-bucket exclusive scan over its 256 chunk-cells ----
__global__ __launch_bounds__(256) void k_scan1(int* __restrict__ histT,
                                               int* __restrict__ tot, int C) {
    __shared__ int sm[256];
    int b = blockIdx.x, t = threadIdx.x;
    size_t base = (size_t)b * C;
    int v = histT[base + t];
    sm[t] = v;
    __syncthreads();
    for (int off = 1; off < 256; off <<= 1) {
        int add = (t >= off) ? sm[t - off] : 0;
        __syncthreads();
        sm[t] += add;
        __syncthreads();
    }
    histT[base + t] = sm[t] - v;          // exclusive within bucket
    if (t == 255) tot[b] = sm[t];
}

// ------- K3: exclusive scan of bucket totals -> bucket bases -------
__global__ __launch_bounds__(1024) void k_scan2(const int* __restrict__ tot,
                                                int* __restrict__ bb, int B) {
    __shared__ int sm[1024];
    int t = threadIdx.x;
    int v = (t < B) ? tot[t] : 0;
    sm[t] = v;
    __syncthreads();
    for (int off = 1; off < 1024; off <<= 1) {
        int add = (t >= off) ? sm[t - off] : 0;
        __syncthreads();
        sm[t] += add;
        __syncthreads();
    }
    if (t < B) {
        bb[t] = sm[t] - v;
        if (t == B - 1) bb[B] = sm[t];
    }
}

// ---------------- K4: scatter edges into bucket-sorted ebuf --------
__global__ __launch_bounds__(256) void k_scatter(const int* __restrict__ ei,
                                                 const float* __restrict__ ew,
                                                 const int* __restrict__ histT,
                                                 const int* __restrict__ bb,
                                                 int2* __restrict__ ebuf,
                                                 int E, int chunk, int B, int C) {
    extern __shared__ int cur[];
    int c = blockIdx.x;
    for (int t = threadIdx.x; t < B; t += 256)
        cur[t] = histT[(size_t)t * C + c] + bb[t];
    __syncthreads();
    int e0 = c * chunk, e1 = min(E, e0 + chunk);
    for (int e = e0 + threadIdx.x; e < e1; e += 256) {
        int s = ei[e];
        int d = ei[E + e];
        float w = ew[e];
        int b = d >> BSH;
        int pos = atomicAdd(&cur[b], 1);   // LDS atomic
        ebuf[pos] = make_int2(s | ((d & 127) << 24), __float_as_int(w));
    }
}

// ---------------- K5: dinv from ebuf (per-bucket LDS sum) ----------
__global__ __launch_bounds__(256) void k_deg(const int2* __restrict__ ebuf,
                                             const int* __restrict__ bb,
                                             float* __restrict__ dinv, int N) {
    __shared__ float dsum[128];
    int b = blockIdx.x, t = threadIdx.x;
    if (t < 128) dsum[t] = 0.0f;
    __syncthreads();
    int p0 = bb[b], p1 = bb[b + 1];
    for (int p = p0 + t; p < p1; p += 256) {
        int2 v = ebuf[p];
        atomicAdd(&dsum[(((unsigned)v.x) >> 24) & 127], __int_as_float(v.y));
    }
    __syncthreads();
    if (t < 128) {
        int i = (b << BSH) + t;
        if (i < N) dinv[i] = rsqrtf(1.0f + dsum[t]);
    }
}

// ---------------- K6: h1 = fp16(x @ W1) via MFMA (W1 conv inline) --
__global__ __launch_bounds__(256) void k_gemm1(const float* __restrict__ x,
                                               const float* __restrict__ W1,
                                               __half* __restrict__ h1, int N) {
    __shared__ _Float16 As[64][136];
    __shared__ _Float16 Bs[64][136];   // Bs[col][k]
    int t = threadIdx.x;
    int wave = t >> 6, lane = t & 63;
    int r0 = blockIdx.x * 64;

    for (int idx = t; idx < DIN * DHID; idx += 256) {
        int k = idx >> 6, c = idx & 63;
        Bs[c][k] = (_Float16)W1[idx];          // W1 is 32KB -> L2-resident
    }
    const float4* xv = (const float4*)x;
    for (int idx = t; idx < 64 * 32; idx += 256) {
        int r = idx >> 5, c4 = idx & 31;
        int rr = r0 + r;
        float4 v = (rr < N) ? xv[(size_t)rr * 32 + c4]
                            : make_float4(0.f, 0.f, 0.f, 0.f);
        As[r][c4 * 4 + 0] = (_Float16)v.x;
        As[r][c4 * 4 + 1] = (_Float16)v.y;
        As[r][c4 * 4 + 2] = (_Float16)v.z;
        As[r][c4 * 4 + 3] = (_Float16)v.w;
    }
    __syncthreads();

    int row = lane & 15;
    int kg  = lane >> 4;
    f32x4 acc0 = {0.f,0.f,0.f,0.f}, acc1 = {0.f,0.f,0.f,0.f};
    f32x4 acc2 = {0.f,0.f,0.f,0.f}, acc3 = {0.f,0.f,0.f,0.f};
#pragma unroll
    for (int kc = 0; kc < 4; ++kc) {
        half8 a = *(const half8*)&As[wave * 16 + row][kc * 32 + kg * 8];
        half8 b0 = *(const half8*)&Bs[ 0 + row][kc * 32 + kg * 8];
        half8 b1 = *(const half8*)&Bs[16 + row][kc * 32 + kg * 8];
        half8 b2 = *(const half8*)&Bs[32 + row][kc * 32 + kg * 8];
        half8 b3 = *(const half8*)&Bs[48 + row][kc * 32 + kg * 8];
        acc0 = __builtin_amdgcn_mfma_f32_16x16x32_f16(a, b0, acc0, 0, 0, 0);
        acc1 = __builtin_amdgcn_mfma_f32_16x16x32_f16(a, b1, acc1, 0, 0, 0);
        acc2 = __builtin_amdgcn_mfma_f32_16x16x32_f16(a, b2, acc2, 0, 0, 0);
        acc3 = __builtin_amdgcn_mfma_f32_16x16x32_f16(a, b3, acc3, 0, 0, 0);
    }
#pragma unroll
    for (int reg = 0; reg < 4; ++reg) {
        int rr = r0 + wave * 16 + kg * 4 + reg;
        if (rr < N) {
            int col = lane & 15;
            size_t base = (size_t)rr * DHID;
            h1[base + col +  0] = __float2half(acc0[reg]);
            h1[base + col + 16] = __float2half(acc1[reg]);
            h1[base + col + 32] = __float2half(acc2[reg]);
            h1[base + col + 48] = __float2half(acc3[reg]);
        }
    }
}

// ------- K7: layer-1 aggregate + bias + ReLU + @W2, per bucket -----
// 512 threads (8 waves); phased 8-edge batches for MLP; LDS fp32 acc.
__global__ __launch_bounds__(512) void k_agg2(const __half* __restrict__ h1h,
                                              const int2* __restrict__ ebuf,
                                              const int* __restrict__ bb,
                                              const float* __restrict__ dinv,
                                              const float* __restrict__ b1,
                                              const float* __restrict__ W2,
                                              float* __restrict__ h2, int N) {
    __shared__ float acc[128][DHID];   // 32 KB
    int b = blockIdx.x, t = threadIdx.x;
    int wave = t >> 6, lane = t & 63;
    for (int q = t; q < 128 * DHID; q += 512) ((float*)acc)[q] = 0.0f;
    __syncthreads();

    int p0 = bb[b], p1 = bb[b + 1];
    int p = p0 + wave;
    // phased batches of 8 edges per wave (strides of 8 waves)
    for (; p + 56 < p1; p += 64) {
        // phase 1: 8 independent edge-record loads (wave-uniform)
        int2 e0 = ebuf[p],      e1 = ebuf[p + 8],  e2 = ebuf[p + 16], e3 = ebuf[p + 24];
        int2 e4 = ebuf[p + 32], e5 = ebuf[p + 40], e6 = ebuf[p + 48], e7 = ebuf[p + 56];
        int x0 = __builtin_amdgcn_readfirstlane(e0.x);
        int x1 = __builtin_amdgcn_readfirstlane(e1.x);
        int x2 = __builtin_amdgcn_readfirstlane(e2.x);
        int x3 = __builtin_amdgcn_readfirstlane(e3.x);
        int x4 = __builtin_amdgcn_readfirstlane(e4.x);
        int x5 = __builtin_amdgcn_readfirstlane(e5.x);
        int x6 = __builtin_amdgcn_readfirstlane(e6.x);
        int x7 = __builtin_amdgcn_readfirstlane(e7.x);
        int s0 = x0 & 0xFFFFFF, s1 = x1 & 0xFFFFFF, s2 = x2 & 0xFFFFFF, s3 = x3 & 0xFFFFFF;
        int s4 = x4 & 0xFFFFFF, s5 = x5 & 0xFFFFFF, s6 = x6 & 0xFFFFFF, s7 = x7 & 0xFFFFFF;
        // phase 2: 8 independent dinv loads
        float d0 = dinv[s0], d1 = dinv[s1], d2 = dinv[s2], d3 = dinv[s3];
        float d4 = dinv[s4], d5 = dinv[s5], d6 = dinv[s6], d7 = dinv[s7];
        // phase 3: 8 independent h1-row gathers (128 B each)
        float h0 = __half2float(h1h[(size_t)s0 * DHID + lane]);
        float h1v = __half2float(h1h[(size_t)s1 * DHID + lane]);
        float h2v_ = __half2float(h1h[(size_t)s2 * DHID + lane]);
        float h3 = __half2float(h1h[(size_t)s3 * DHID + lane]);
        float h4 = __half2float(h1h[(size_t)s4 * DHID + lane]);
        float h5 = __half2float(h1h[(size_t)s5 * DHID + lane]);
        float h6 = __half2float(h1h[(size_t)s6 * DHID + lane]);
        float h7 = __half2float(h1h[(size_t)s7 * DHID + lane]);
        // phase 4: 8 LDS adds (conflict-free: 64 lanes -> 64 consecutive floats)
        float w0 = __uint_as_float(__builtin_amdgcn_readfirstlane(e0.y)) * d0;
        float w1 = __uint_as_float(__builtin_amdgcn_readfirstlane(e1.y)) * d1;
        float w2 = __uint_as_float(__builtin_amdgcn_readfirstlane(e2.y)) * d2;
        float w3 = __uint_as_float(__builtin_amdgcn_readfirstlane(e3.y)) * d3;
        float w4 = __uint_as_float(__builtin_amdgcn_readfirstlane(e4.y)) * d4;
        float w5 = __uint_as_float(__builtin_amdgcn_readfirstlane(e5.y)) * d5;
        float w6 = __uint_as_float(__builtin_amdgcn_readfirstlane(e6.y)) * d6;
        float w7 = __uint_as_float(__builtin_amdgcn_readfirstlane(e7.y)) * d7;
        atomicAdd(&acc[(((unsigned)x0) >> 24) & 127][lane], w0 * h0);
        atomicAdd(&acc[(((unsigned)x1) >> 24) & 127][lane], w1 * h1v);
        atomicAdd(&acc[(((unsigned)x2) >> 24) & 127][lane], w2 * h2v_);
        atomicAdd(&acc[(((unsigned)x3) >> 24) & 127][lane], w3 * h3);
        atomicAdd(&acc[(((unsigned)x4) >> 24) & 127][lane], w4 * h4);
        atomicAdd(&acc[(((unsigned)x5) >> 24) & 127][lane], w5 * h5);
        atomicAdd(&acc[(((unsigned)x6) >> 24) & 127][lane], w6 * h6);
        atomicAdd(&acc[(((unsigned)x7) >> 24) & 127][lane], w7 * h7);
    }
    for (; p < p1; p += 8) {
        int2 ev = ebuf[p];
        int vx = __builtin_amdgcn_readfirstlane(ev.x);
        int src = vx & 0xFFFFFF;
        float wn = __uint_as_float(__builtin_amdgcn_readfirstlane(ev.y)) * dinv[src];
        float hv = __half2float(h1h[(size_t)src * DHID + lane]);
        atomicAdd(&acc[(((unsigned)vx) >> 24) & 127][lane], wn * hv);
    }
    __syncthreads();

    // epilogue: 8 waves x 16 nodes
    float bias = b1[lane];
    float w2a = W2[lane * 2];
    float w2b = W2[lane * 2 + 1];
    for (int k = 0; k < 16; ++k) {
        int ln = wave * 16 + k;
        int i = (b << BSH) + ln;
        if (i >= N) break;
        float di = dinv[i];
        float self = __half2float(h1h[(size_t)i * DHID + lane]);
        float a = (acc[ln][lane] + di * self) * di;
        a = fmaxf(a + bias, 0.0f);
        float o0 = a * w2a, o1 = a * w2b;
        for (int off = 32; off > 0; off >>= 1) {
            o0 += __shfl_xor(o0, off);
            o1 += __shfl_xor(o1, off);
        }
        if (lane == 0) {
            h2[i * 2]     = o0;
            h2[i * 2 + 1] = o1;
        }
    }
}

// ------- K8: layer-2 propagate per bucket: acc[128][2] in LDS ------
__global__ __launch_bounds__(256) void k_prop3(const float* __restrict__ h2,
                                               const int2* __restrict__ ebuf,
                                               const int* __restrict__ bb,
                                               const float* __restrict__ dinv,
                                               const float* __restrict__ b2,
                                               float* __restrict__ out, int N) {
    __shared__ float acc[128][2];
    const float2* h2v = (const float2*)h2;
    int b = blockIdx.x, t = threadIdx.x;
    if (t < 128) { acc[t][0] = 0.0f; acc[t][1] = 0.0f; }
    __syncthreads();
    int p0 = bb[b], p1 = bb[b + 1];
    for (int p = p0 + t; p < p1; p += 256) {
        int2 v = ebuf[p];
        int src = v.x & 0xFFFFFF;
        int ln = (((unsigned)v.x) >> 24) & 127;
        float wn = __int_as_float(v.y) * dinv[src];
        float2 hv = h2v[src];
        atomicAdd(&acc[ln][0], wn * hv.x);
        atomicAdd(&acc[ln][1], wn * hv.y);
    }
    __syncthreads();
    if (t < 128) {
        int i = (b << BSH) + t;
        if (i < N) {
            float di = dinv[i];
            out[i * 2]     = di * (acc[t][0] + di * h2[i * 2])     + b2[0];
            out[i * 2 + 1] = di * (acc[t][1] + di * h2[i * 2 + 1]) + b2[1];
        }
    }
}

extern "C" void kernel_launch(void* const* d_in, const int* in_sizes, int n_in,
                              void* d_out, int out_size, void* d_ws, size_t ws_size,
                              hipStream_t stream) {
    const float* x  = (const float*)d_in[0];
    const int*   ei = (const int*)d_in[1];     // int32 per harness contract
    const float* ew = (const float*)d_in[2];
    const float* W1 = (const float*)d_in[3];
    const float* b1 = (const float*)d_in[4];
    const float* W2 = (const float*)d_in[5];
    const float* b2 = (const float*)d_in[6];
    float* out = (float*)d_out;

    const int N = in_sizes[0] / DIN;   // 100000
    const int E = in_sizes[2];         // 3200000

    const int C = 256;                 // edge chunks
    const int B = (N + 127) >> BSH;    // 782 buckets of 128 nodes
    const int chunk = (E + C - 1) / C;

    // workspace layout (~40.5 MB)
    char* w0 = (char*)d_ws;
    float* dinv  = (float*)w0;                      // N floats
    int*   histT = (int*)(dinv + N);                // B*C ints (800 KB)
    int*   tot   = histT + (size_t)B * C;           // B ints
    int*   bb    = tot + B;                         // B+1 ints
    size_t off_ebuf = ((size_t)((char*)(bb + B + 1) - w0) + 15) & ~(size_t)15;
    int2*  ebuf = (int2*)(w0 + off_ebuf);           // E pairs (25.6 MB)
    __half* h1  = (__half*)(ebuf + E);              // N*64 fp16 (12.8 MB)
    float* h2   = (float*)(h1 + (size_t)N * DHID);  // N*2 fp32

    size_t ldsB = (size_t)B * sizeof(int);

    k_hist<<<C, 256, ldsB, stream>>>(ei, histT, E, chunk, B, C);
    k_scan1<<<B, 256, 0, stream>>>(histT, tot, C);
    k_scan2<<<1, 1024, 0, stream>>>(tot, bb, B);
    k_scatter<<<C, 256, ldsB, stream>>>(ei, ew, histT, bb, ebuf, E, chunk, B, C);
    k_deg<<<B, 256, 0, stream>>>(ebuf, bb, dinv, N);

    const int GB = (N + 63) / 64;
    k_gemm1<<<GB, 256, 0, stream>>>(x, W1, h1, N);

    k_agg2<<<B, 512, 0, stream>>>(h1, ebuf, bb, dinv, b1, W2, h2, N);
    k_prop3<<<B, 256, 0, stream>>>(h2, ebuf, bb, dinv, b2, out, N);
}

// Round 12
// 379.483 us; speedup vs baseline: 4.2769x; 4.2727x over previous
//
#include <hip/hip_runtime.h>
#include <hip/hip_bf16.h>
#include <hip/hip_fp16.h>

// 2-layer GCN, N=100000 nodes, E=3.2M edges, dims 128 -> 64 -> 2, fp32.
// R12: REVERT to R9's per-node CSR pipeline (403us). R10/R11's bucket-LDS
// aggregation pinned at 1360us regardless of occupancy/ILP — structurally
// latency-poisoned. Changes vs R9: (a) W1 fp32->fp16 folded into k_gemm1
// staging (k_w1h launch removed); (b) k_agg1 unroll 4->8 (VGPR headroom,
// 2x memory-level parallelism on the h1 gather stream).

#define DIN  128
#define DHID 64
#define BSH  7                    // bucket shift: 128 nodes/bucket
#define BCAP 5000                 // LDS staging capacity (edges/bucket)

typedef _Float16 half8 __attribute__((ext_vector_type(8)));
typedef float    f32x4 __attribute__((ext_vector_type(4)));

// ---------------- K1: per-chunk coarse histogram (LDS only) --------
__global__ __launch_bounds__(256) void k_hist(const int* __restrict__ ei,
                                              int* __restrict__ histT,
                                              int E, int chunk, int B, int C) {
    extern __shared__ int h[];
    for (int t = threadIdx.x; t < B; t += 256) h[t] = 0;
    __syncthreads();
    int c = blockIdx.x;
    int e0 = c * chunk, e1 = min(E, e0 + chunk);
    for (int e = e0 + threadIdx.x; e < e1; e += 256)
        atomicAdd(&h[ei[E + e] >> BSH], 1);
    __syncthreads();
    for (int t = threadIdx.x; t < B; t += 256) histT[(size_t)t * C + c] = h[t];
}

// ------- K2: per-bucket exclusive scan over its 256 chunk-cells ----
__global__ __launch_bounds__(256) void k_scan1(int* __restrict__ histT,
                                               int* __restrict__ tot, int C) {
    __shared__ int sm[256];
    int b = blockIdx.x, t = threadIdx.x;
    size_t base = (size_t)b * C;
    int v = histT[base + t];
    sm[t] = v;
    __syncthreads();
    for (int off = 1; off < 256; off <<= 1) {
        int add = (t >= off) ? sm[t - off] : 0;
        __syncthreads();
        sm[t] += add;
        __syncthreads();
    }
    histT[base + t] = sm[t] - v;          // exclusive within bucket
    if (t == 255) tot[b] = sm[t];
}

// ------- K3: exclusive scan of bucket totals -> bucket bases -------
__global__ __launch_bounds__(1024) void k_scan2(const int* __restrict__ tot,
                                                int* __restrict__ bb, int B) {
    __shared__ int sm[1024];
    int t = threadIdx.x;
    int v = (t < B) ? tot[t] : 0;
    sm[t] = v;
    __syncthreads();
    for (int off = 1; off < 1024; off <<= 1) {
        int add = (t >= off) ? sm[t - off] : 0;
        __syncthreads();
        sm[t] += add;
        __syncthreads();
    }
    if (t < B) {
        bb[t] = sm[t] - v;
        if (t == B - 1) bb[B] = sm[t];
    }
}

// ---------------- K4: scatter edges into bucket-sorted ebuf --------
__global__ __launch_bounds__(256) void k_scatter(const int* __restrict__ ei,
                                                 const float* __restrict__ ew,
                                                 const int* __restrict__ histT,
                                                 const int* __restrict__ bb,
                                                 int2* __restrict__ ebuf,
                                                 int E, int chunk, int B, int C) {
    extern __shared__ int cur[];
    int c = blockIdx.x;
    for (int t = threadIdx.x; t < B; t += 256)
        cur[t] = histT[(size_t)t * C + c] + bb[t];
    __syncthreads();
    int e0 = c * chunk, e1 = min(E, e0 + chunk);
    for (int e = e0 + threadIdx.x; e < e1; e += 256) {
        int s = ei[e];
        int d = ei[E + e];
        float w = ew[e];
        int b = d >> BSH;
        int pos = atomicAdd(&cur[b], 1);   // LDS atomic
        ebuf[pos] = make_int2(s | ((d & 127) << 24), __float_as_int(w));
    }
}

// ---------------- K5: per-bucket CSR build (rp, dinv, csw) ---------
__global__ __launch_bounds__(256) void k_build(const int2* __restrict__ ebuf,
                                               const int* __restrict__ bb,
                                               int* __restrict__ rp,
                                               float* __restrict__ dinv,
                                               int2* __restrict__ csw,
                                               int N, int E) {
    __shared__ int2  stage[BCAP];   // 40 KB
    __shared__ int   cnt[128];
    __shared__ float dsum[128];
    __shared__ int   lrp[128];
    __shared__ int   cur[128];
    __shared__ int   sm[128];
    int b = blockIdx.x, t = threadIdx.x;
    if (t < 128) { cnt[t] = 0; dsum[t] = 0.0f; cur[t] = 0; }
    __syncthreads();
    int p0 = bb[b], p1 = bb[b + 1];
    int m = p1 - p0;
    bool fits = (m <= BCAP);
    for (int p = p0 + t; p < p1; p += 256) {
        int2 v = ebuf[p];
        if (fits) stage[p - p0] = v;
        int ln = (((unsigned)v.x) >> 24) & 127;
        atomicAdd(&cnt[ln], 1);
        atomicAdd(&dsum[ln], __int_as_float(v.y));
    }
    __syncthreads();
    if (t < 128) {
        int cv = cnt[t];
        sm[t] = cv;
        __syncthreads();
        for (int off = 1; off < 128; off <<= 1) {
            int add = (t >= off) ? sm[t - off] : 0;
            __syncthreads();
            sm[t] += add;
            __syncthreads();
        }
        lrp[t] = sm[t] - cv + p0;     // absolute csw base for local node t
        int d = (b << BSH) + t;
        if (d < N) {
            rp[d]   = lrp[t];
            dinv[d] = rsqrtf(1.0f + dsum[t]);
        }
        if (b == 0 && t == 0) rp[N] = E;
    } else {
        __syncthreads();
        for (int off = 1; off < 128; off <<= 1) { __syncthreads(); __syncthreads(); }
    }
    __syncthreads();
    for (int q = t; q < m; q += 256) {
        int2 v = fits ? stage[q] : ebuf[p0 + q];
        int ln = (((unsigned)v.x) >> 24) & 127;
        int r = atomicAdd(&cur[ln], 1);   // LDS atomic
        csw[lrp[ln] + r] = make_int2(v.x & 0xFFFFFF, v.y);  // raw w
    }
}

// ---------------- K6: h1 = fp16(x @ W1) via MFMA (W1 conv inline) --
__global__ __launch_bounds__(256) void k_gemm1(const float* __restrict__ x,
                                               const float* __restrict__ W1,
                                               __half* __restrict__ h1, int N) {
    __shared__ _Float16 As[64][136];
    __shared__ _Float16 Bs[64][136];   // Bs[col][k]
    int t = threadIdx.x;
    int wave = t >> 6, lane = t & 63;
    int r0 = blockIdx.x * 64;

    for (int idx = t; idx < DIN * DHID; idx += 256) {
        int k = idx >> 6, c = idx & 63;
        Bs[c][k] = (_Float16)W1[idx];          // W1 32KB -> L2-resident
    }
    const float4* xv = (const float4*)x;
    for (int idx = t; idx < 64 * 32; idx += 256) {
        int r = idx >> 5, c4 = idx & 31;
        int rr = r0 + r;
        float4 v = (rr < N) ? xv[(size_t)rr * 32 + c4]
                            : make_float4(0.f, 0.f, 0.f, 0.f);
        As[r][c4 * 4 + 0] = (_Float16)v.x;
        As[r][c4 * 4 + 1] = (_Float16)v.y;
        As[r][c4 * 4 + 2] = (_Float16)v.z;
        As[r][c4 * 4 + 3] = (_Float16)v.w;
    }
    __syncthreads();

    int row = lane & 15;
    int kg  = lane >> 4;
    f32x4 acc0 = {0.f,0.f,0.f,0.f}, acc1 = {0.f,0.f,0.f,0.f};
    f32x4 acc2 = {0.f,0.f,0.f,0.f}, acc3 = {0.f,0.f,0.f,0.f};
#pragma unroll
    for (int kc = 0; kc < 4; ++kc) {
        half8 a = *(const half8*)&As[wave * 16 + row][kc * 32 + kg * 8];
        half8 b0 = *(const half8*)&Bs[ 0 + row][kc * 32 + kg * 8];
        half8 b1 = *(const half8*)&Bs[16 + row][kc * 32 + kg * 8];
        half8 b2 = *(const half8*)&Bs[32 + row][kc * 32 + kg * 8];
        half8 b3 = *(const half8*)&Bs[48 + row][kc * 32 + kg * 8];
        acc0 = __builtin_amdgcn_mfma_f32_16x16x32_f16(a, b0, acc0, 0, 0, 0);
        acc1 = __builtin_amdgcn_mfma_f32_16x16x32_f16(a, b1, acc1, 0, 0, 0);
        acc2 = __builtin_amdgcn_mfma_f32_16x16x32_f16(a, b2, acc2, 0, 0, 0);
        acc3 = __builtin_amdgcn_mfma_f32_16x16x32_f16(a, b3, acc3, 0, 0, 0);
    }
#pragma unroll
    for (int reg = 0; reg < 4; ++reg) {
        int rr = r0 + wave * 16 + kg * 4 + reg;
        if (rr < N) {
            int col = lane & 15;
            size_t base = (size_t)rr * DHID;
            h1[base + col +  0] = __float2half(acc0[reg]);
            h1[base + col + 16] = __float2half(acc1[reg]);
            h1[base + col + 32] = __float2half(acc2[reg]);
            h1[base + col + 48] = __float2half(acc3[reg]);
        }
    }
}

// ------- K7: fused layer-1 aggregate + bias + ReLU + @W2 -----------
// one wave per node; lane = feature; wave-uniform scalar edge loads,
// one coalesced 128B fp16-row gather per edge; 8-deep batches for MLP.
__global__ __launch_bounds__(256) void k_agg1(const __half* __restrict__ h1h,
                                              const int* __restrict__ rp,
                                              const int2* __restrict__ csw,
                                              const float* __restrict__ dinv,
                                              const float* __restrict__ b1,
                                              const float* __restrict__ W2,
                                              float* __restrict__ h2, int N) {
    int lane = threadIdx.x & 63;
    int i = (blockIdx.x * 256 + threadIdx.x) >> 6;
    if (i >= N) return;
    float bias = b1[lane];
    float w2a = W2[lane * 2];
    float w2b = W2[lane * 2 + 1];
    int s0 = __builtin_amdgcn_readfirstlane(rp[i]);
    int e0 = __builtin_amdgcn_readfirstlane(rp[i + 1]);
    float acc = 0.0f;
    int p = s0;
    for (; p + 8 <= e0; p += 8) {
        int2 eA = csw[p],     eB = csw[p + 1], eC = csw[p + 2], eD = csw[p + 3];
        int2 eE = csw[p + 4], eF = csw[p + 5], eG = csw[p + 6], eH = csw[p + 7];
        int sA = __builtin_amdgcn_readfirstlane(eA.x);
        int sB = __builtin_amdgcn_readfirstlane(eB.x);
        int sC = __builtin_amdgcn_readfirstlane(eC.x);
        int sD = __builtin_amdgcn_readfirstlane(eD.x);
        int sE = __builtin_amdgcn_readfirstlane(eE.x);
        int sF = __builtin_amdgcn_readfirstlane(eF.x);
        int sG = __builtin_amdgcn_readfirstlane(eG.x);
        int sH = __builtin_amdgcn_readfirstlane(eH.x);
        float wA = __uint_as_float(__builtin_amdgcn_readfirstlane(eA.y)) * dinv[sA];
        float wB = __uint_as_float(__builtin_amdgcn_readfirstlane(eB.y)) * dinv[sB];
        float wC = __uint_as_float(__builtin_amdgcn_readfirstlane(eC.y)) * dinv[sC];
        float wD = __uint_as_float(__builtin_amdgcn_readfirstlane(eD.y)) * dinv[sD];
        float wE = __uint_as_float(__builtin_amdgcn_readfirstlane(eE.y)) * dinv[sE];
        float wF = __uint_as_float(__builtin_amdgcn_readfirstlane(eF.y)) * dinv[sF];
        float wG = __uint_as_float(__builtin_amdgcn_readfirstlane(eG.y)) * dinv[sG];
        float wH = __uint_as_float(__builtin_amdgcn_readfirstlane(eH.y)) * dinv[sH];
        float hA = __half2float(h1h[(size_t)sA * DHID + lane]);
        float hB = __half2float(h1h[(size_t)sB * DHID + lane]);
        float hC = __half2float(h1h[(size_t)sC * DHID + lane]);
        float hD = __half2float(h1h[(size_t)sD * DHID + lane]);
        float hE = __half2float(h1h[(size_t)sE * DHID + lane]);
        float hF = __half2float(h1h[(size_t)sF * DHID + lane]);
        float hG = __half2float(h1h[(size_t)sG * DHID + lane]);
        float hH = __half2float(h1h[(size_t)sH * DHID + lane]);
        acc = fmaf(wA, hA, acc);
        acc = fmaf(wB, hB, acc);
        acc = fmaf(wC, hC, acc);
        acc = fmaf(wD, hD, acc);
        acc = fmaf(wE, hE, acc);
        acc = fmaf(wF, hF, acc);
        acc = fmaf(wG, hG, acc);
        acc = fmaf(wH, hH, acc);
    }
    for (; p + 4 <= e0; p += 4) {
        int2 eA = csw[p], eB = csw[p + 1], eC = csw[p + 2], eD = csw[p + 3];
        int sA = __builtin_amdgcn_readfirstlane(eA.x);
        int sB = __builtin_amdgcn_readfirstlane(eB.x);
        int sC = __builtin_amdgcn_readfirstlane(eC.x);
        int sD = __builtin_amdgcn_readfirstlane(eD.x);
        float wA = __uint_as_float(__builtin_amdgcn_readfirstlane(eA.y)) * dinv[sA];
        float wB = __uint_as_float(__builtin_amdgcn_readfirstlane(eB.y)) * dinv[sB];
        float wC = __uint_as_float(__builtin_amdgcn_readfirstlane(eC.y)) * dinv[sC];
        float wD = __uint_as_float(__builtin_amdgcn_readfirstlane(eD.y)) * dinv[sD];
        float hA = __half2float(h1h[(size_t)sA * DHID + lane]);
        float hB = __half2float(h1h[(size_t)sB * DHID + lane]);
        float hC = __half2float(h1h[(size_t)sC * DHID + lane]);
        float hD = __half2float(h1h[(size_t)sD * DHID + lane]);
        acc = fmaf(wA, hA, acc);
        acc = fmaf(wB, hB, acc);
        acc = fmaf(wC, hC, acc);
        acc = fmaf(wD, hD, acc);
    }
    for (; p < e0; ++p) {
        int2 eA = csw[p];
        int sA = __builtin_amdgcn_readfirstlane(eA.x);
        float wA = __uint_as_float(__builtin_amdgcn_readfirstlane(eA.y)) * dinv[sA];
        acc = fmaf(wA, __half2float(h1h[(size_t)sA * DHID + lane]), acc);
    }
    // self-loop + dst-side norm: di*(edge_sum + di*self)
    float di = dinv[i];
    acc = (acc + di * __half2float(h1h[(size_t)i * DHID + lane])) * di;
    acc = fmaxf(acc + bias, 0.0f);
    float o0 = acc * w2a, o1 = acc * w2b;
    for (int off = 32; off > 0; off >>= 1) {
        o0 += __shfl_xor(o0, off);
        o1 += __shfl_xor(o1, off);
    }
    if (lane == 0) {
        h2[i * 2]     = o0;
        h2[i * 2 + 1] = o1;
    }
}

// ------- K8: layer-2 propagate: out = di*(sum + di*self) + b2 ------
__global__ __launch_bounds__(256) void k_prop2(const float* __restrict__ h2,
                                               const int* __restrict__ rp,
                                               const int2* __restrict__ csw,
                                               const float* __restrict__ dinv,
                                               const float* __restrict__ b2,
                                               float* __restrict__ out, int N) {
    const float2* h2v = (const float2*)h2;
    int lane = threadIdx.x & 63;
    int i = (blockIdx.x * 256 + threadIdx.x) >> 6;
    if (i >= N) return;
    float b20 = b2[0], b21 = b2[1];
    int s0 = rp[i], e0 = rp[i + 1];
    float a0 = 0.0f, a1 = 0.0f;
    for (int p = s0 + lane; p < e0; p += 64) {
        int2 ed = csw[p];
        float w = __int_as_float(ed.y) * dinv[ed.x];  // raw w * dinv[src]
        float2 hv = h2v[ed.x];
        a0 = fmaf(w, hv.x, a0);
        a1 = fmaf(w, hv.y, a1);
    }
    for (int off = 32; off > 0; off >>= 1) {
        a0 += __shfl_xor(a0, off);
        a1 += __shfl_xor(a1, off);
    }
    if (lane == 0) {
        float di = dinv[i];
        out[i * 2]     = di * (a0 + di * h2[i * 2])     + b2[0];
        out[i * 2 + 1] = di * (a1 + di * h2[i * 2 + 1]) + b2[1];
    }
}

extern "C" void kernel_launch(void* const* d_in, const int* in_sizes, int n_in,
                              void* d_out, int out_size, void* d_ws, size_t ws_size,
                              hipStream_t stream) {
    const float* x  = (const float*)d_in[0];
    const int*   ei = (const int*)d_in[1];     // int32 per harness contract
    const float* ew = (const float*)d_in[2];
    const float* W1 = (const float*)d_in[3];
    const float* b1 = (const float*)d_in[4];
    const float* W2 = (const float*)d_in[5];
    const float* b2 = (const float*)d_in[6];
    float* out = (float*)d_out;

    const int N = in_sizes[0] / DIN;   // 100000
    const int E = in_sizes[2];         // 3200000

    const int C = 256;                 // edge chunks
    const int B = (N + 127) >> BSH;    // 782 buckets of 128 nodes
    const int chunk = (E + C - 1) / C;

    // workspace layout (~53 MB; ebuf aliased by h1/h2 after k_build)
    char* w0 = (char*)d_ws;
    float* dinv  = (float*)w0;                      // N floats
    int*   rp    = (int*)(dinv + N);                // N+1 ints (+3 pad)
    int*   histT = rp + (N + 4);                    // B*C ints (800 KB)
    int*   tot   = histT + (size_t)B * C;           // B ints
    int*   bb    = tot + B;                         // B+1 ints
    size_t off_csw = ((size_t)((char*)(bb + B + 1) - w0) + 15) & ~(size_t)15;
    int2*  csw  = (int2*)(w0 + off_csw);            // E pairs (25.6 MB)
    int2*  ebuf = csw + E;                          // E pairs (25.6 MB)
    __half* h1  = (__half*)ebuf;                    // alias: N*64 fp16 (12.8 MB)
    float* h2   = (float*)(h1 + (size_t)N * DHID);  // alias: N*2 fp32

    size_t ldsB = (size_t)B * sizeof(int);

    k_hist<<<C, 256, ldsB, stream>>>(ei, histT, E, chunk, B, C);
    k_scan1<<<B, 256, 0, stream>>>(histT, tot, C);
    k_scan2<<<1, 1024, 0, stream>>>(tot, bb, B);
    k_scatter<<<C, 256, ldsB, stream>>>(ei, ew, histT, bb, ebuf, E, chunk, B, C);
    k_build<<<B, 256, 0, stream>>>(ebuf, bb, rp, dinv, csw, N, E);

    const int GB = (N + 63) / 64;
    k_gemm1<<<GB, 256, 0, stream>>>(x, W1, h1, N);

    const int GW = ((size_t)N * 64 + 255) / 256;   // one wave per node
    k_agg1<<<GW, 256, 0, stream>>>(h1, rp, csw, dinv, b1, W2, h2, N);
    k_prop2<<<GW, 256, 0, stream>>>(h2, rp, csw, dinv, b2, out, N);
}

// Round 13
// 377.129 us; speedup vs baseline: 4.3036x; 1.0062x over previous
//
#include <hip/hip_runtime.h>
#include <hip/hip_bf16.h>
#include <hip/hip_fp16.h>

// 2-layer GCN, N=100000 nodes, E=3.2M edges, dims 128 -> 64 -> 2, fp32.
// R13: k_scatter rewritten as LDS slot-reordered placement (the old version
// scattered each wave's 64 stores across ~64 cache lines over 25.6MB ->
// write-amp past the 4MB per-XCD L2, est ~100us hidden cost). New flow per
// 12.5K-edge chunk: count -> scan -> place edge-INDICES into bucket-ordered
// LDS slots -> slot-ordered writeout (128B full-line bursts). k_build 512
// threads + branch-free scan; k_hist 1024 threads. agg1/gemm1/prop2 as R12.

#define DIN  128
#define DHID 64
#define BSH  7                    // bucket shift: 128 nodes/bucket
#define BCAP 5000                 // k_build LDS staging capacity (edges)
#define SCHUNK 12544              // k_scatter LDS slot capacity (>= E/C)
#define BMAX 800                  // >= B = ceil(N/128) = 782

typedef _Float16 half8 __attribute__((ext_vector_type(8)));
typedef float    f32x4 __attribute__((ext_vector_type(4)));

// ---------------- K1: per-chunk coarse histogram (LDS only) --------
__global__ __launch_bounds__(1024) void k_hist(const int* __restrict__ ei,
                                               int* __restrict__ histT,
                                               int E, int chunk, int B, int C) {
    extern __shared__ int h[];
    for (int t = threadIdx.x; t < B; t += 1024) h[t] = 0;
    __syncthreads();
    int c = blockIdx.x;
    int e0 = c * chunk, e1 = min(E, e0 + chunk);
    for (int e = e0 + threadIdx.x; e < e1; e += 1024)
        atomicAdd(&h[ei[E + e] >> BSH], 1);
    __syncthreads();
    for (int t = threadIdx.x; t < B; t += 1024) histT[(size_t)t * C + c] = h[t];
}

// ------- K2: per-bucket exclusive scan over its C chunk-cells ------
__global__ __launch_bounds__(256) void k_scan1(int* __restrict__ histT,
                                               int* __restrict__ tot, int C) {
    __shared__ int sm[256];
    int b = blockIdx.x, t = threadIdx.x;
    size_t base = (size_t)b * C;
    int v = histT[base + t];
    sm[t] = v;
    __syncthreads();
    for (int off = 1; off < 256; off <<= 1) {
        int add = (t >= off) ? sm[t - off] : 0;
        __syncthreads();
        sm[t] += add;
        __syncthreads();
    }
    histT[base + t] = sm[t] - v;          // exclusive within bucket
    if (t == 255) tot[b] = sm[t];
}

// ------- K3: exclusive scan of bucket totals -> bucket bases -------
__global__ __launch_bounds__(1024) void k_scan2(const int* __restrict__ tot,
                                                int* __restrict__ bb, int B) {
    __shared__ int sm[1024];
    int t = threadIdx.x;
    int v = (t < B) ? tot[t] : 0;
    sm[t] = v;
    __syncthreads();
    for (int off = 1; off < 1024; off <<= 1) {
        int add = (t >= off) ? sm[t - off] : 0;
        __syncthreads();
        sm[t] += add;
        __syncthreads();
    }
    if (t < B) {
        bb[t] = sm[t] - v;
        if (t == B - 1) bb[B] = sm[t];
    }
}

// ---------------- K4: LDS slot-reordered scatter -------------------
// Per chunk: count -> scan -> place edge indices into bucket-ordered
// slots -> slot-ordered coalesced writeout to ebuf.
__global__ __launch_bounds__(1024) void k_scatter(const int* __restrict__ ei,
                                                  const float* __restrict__ ew,
                                                  const int* __restrict__ histT,
                                                  const int* __restrict__ bb,
                                                  int2* __restrict__ ebuf,
                                                  int E, int chunk, int B, int C) {
    __shared__ int eidx[SCHUNK];          // 50 KB (also scan temp)
    __shared__ int lbase[BMAX];
    __shared__ int lcur[BMAX];
    __shared__ int gbase[BMAX];
    int c = blockIdx.x, t = threadIdx.x;
    int e0 = c * chunk, e1 = min(E, e0 + chunk), m = e1 - e0;

    for (int b = t; b < B; b += 1024) lcur[b] = 0;
    __syncthreads();
    // pass 1: per-bucket counts
    for (int q = t; q < m; q += 1024)
        atomicAdd(&lcur[ei[E + e0 + q] >> BSH], 1);
    __syncthreads();
    // scan counts (1024-wide Hillis-Steele in eidx[0..1023])
    int v = (t < B) ? lcur[t] : 0;
    eidx[t] = v;
    __syncthreads();
    for (int off = 1; off < 1024; off <<= 1) {
        int add = (t >= off) ? eidx[t - off] : 0;
        __syncthreads();
        eidx[t] += add;
        __syncthreads();
    }
    if (t < B) {
        lbase[t] = eidx[t] - v;
        gbase[t] = histT[(size_t)t * C + c] + bb[t];
        lcur[t] = 0;
    }
    __syncthreads();
    // pass 2: place edge indices into bucket-ordered slots (dst re-read L2-hot)
    for (int q = t; q < m; q += 1024) {
        int b = ei[E + e0 + q] >> BSH;
        int pos = lbase[b] + atomicAdd(&lcur[b], 1);
        eidx[pos] = q;
    }
    __syncthreads();
    // pass 3: slot-ordered writeout (consecutive slots -> consecutive ebuf)
    for (int q = t; q < m; q += 1024) {
        int e = e0 + eidx[q];
        int s = ei[e];
        int d = ei[E + e];
        float w = ew[e];
        int b = d >> BSH;
        int gpos = gbase[b] + (q - lbase[b]);
        ebuf[gpos] = make_int2(s | ((d & 127) << 24), __float_as_int(w));
    }
}

// ---------------- K5: per-bucket CSR build (rp, dinv, csw) ---------
__global__ __launch_bounds__(512) void k_build(const int2* __restrict__ ebuf,
                                               const int* __restrict__ bb,
                                               int* __restrict__ rp,
                                               float* __restrict__ dinv,
                                               int2* __restrict__ csw,
                                               int N, int E) {
    __shared__ int2  stage[BCAP];   // 40 KB
    __shared__ int   cnt[128];
    __shared__ float dsum[128];
    __shared__ int   lrp[128];
    __shared__ int   cur[128];
    __shared__ int   sm[512];
    int b = blockIdx.x, t = threadIdx.x;
    if (t < 128) { cnt[t] = 0; dsum[t] = 0.0f; cur[t] = 0; }
    __syncthreads();
    int p0 = bb[b], p1 = bb[b + 1];
    int m = p1 - p0;
    bool fits = (m <= BCAP);
    for (int p = p0 + t; p < p1; p += 512) {
        int2 v = ebuf[p];
        if (fits) stage[p - p0] = v;
        int ln = (((unsigned)v.x) >> 24) & 127;
        atomicAdd(&cnt[ln], 1);
        atomicAdd(&dsum[ln], __int_as_float(v.y));
    }
    __syncthreads();
    // branch-free scan of 128 counts (threads >=128 carry zeros)
    int cv = (t < 128) ? cnt[t] : 0;
    sm[t] = cv;
    __syncthreads();
    for (int off = 1; off < 128; off <<= 1) {
        int add = (t >= off) ? sm[t - off] : 0;
        __syncthreads();
        sm[t] += add;
        __syncthreads();
    }
    if (t < 128) {
        lrp[t] = sm[t] - cv + p0;     // absolute csw base for local node t
        int d = (b << BSH) + t;
        if (d < N) {
            rp[d]   = lrp[t];
            dinv[d] = rsqrtf(1.0f + dsum[t]);
        }
    }
    if (b == 0 && t == 0) rp[N] = E;
    __syncthreads();
    for (int q = t; q < m; q += 512) {
        int2 v = fits ? stage[q] : ebuf[p0 + q];
        int ln = (((unsigned)v.x) >> 24) & 127;
        int r = atomicAdd(&cur[ln], 1);   // LDS atomic
        csw[lrp[ln] + r] = make_int2(v.x & 0xFFFFFF, v.y);  // raw w
    }
}

// ---------------- K6: h1 = fp16(x @ W1) via MFMA (W1 conv inline) --
__global__ __launch_bounds__(256) void k_gemm1(const float* __restrict__ x,
                                               const float* __restrict__ W1,
                                               __half* __restrict__ h1, int N) {
    __shared__ _Float16 As[64][136];
    __shared__ _Float16 Bs[64][136];   // Bs[col][k]
    int t = threadIdx.x;
    int wave = t >> 6, lane = t & 63;
    int r0 = blockIdx.x * 64;

    for (int idx = t; idx < DIN * DHID; idx += 256) {
        int k = idx >> 6, c = idx & 63;
        Bs[c][k] = (_Float16)W1[idx];          // W1 32KB -> L2-resident
    }
    const float4* xv = (const float4*)x;
    for (int idx = t; idx < 64 * 32; idx += 256) {
        int r = idx >> 5, c4 = idx & 31;
        int rr = r0 + r;
        float4 v = (rr < N) ? xv[(size_t)rr * 32 + c4]
                            : make_float4(0.f, 0.f, 0.f, 0.f);
        As[r][c4 * 4 + 0] = (_Float16)v.x;
        As[r][c4 * 4 + 1] = (_Float16)v.y;
        As[r][c4 * 4 + 2] = (_Float16)v.z;
        As[r][c4 * 4 + 3] = (_Float16)v.w;
    }
    __syncthreads();

    int row = lane & 15;
    int kg  = lane >> 4;
    f32x4 acc0 = {0.f,0.f,0.f,0.f}, acc1 = {0.f,0.f,0.f,0.f};
    f32x4 acc2 = {0.f,0.f,0.f,0.f}, acc3 = {0.f,0.f,0.f,0.f};
#pragma unroll
    for (int kc = 0; kc < 4; ++kc) {
        half8 a = *(const half8*)&As[wave * 16 + row][kc * 32 + kg * 8];
        half8 b0 = *(const half8*)&Bs[ 0 + row][kc * 32 + kg * 8];
        half8 b1 = *(const half8*)&Bs[16 + row][kc * 32 + kg * 8];
        half8 b2 = *(const half8*)&Bs[32 + row][kc * 32 + kg * 8];
        half8 b3 = *(const half8*)&Bs[48 + row][kc * 32 + kg * 8];
        acc0 = __builtin_amdgcn_mfma_f32_16x16x32_f16(a, b0, acc0, 0, 0, 0);
        acc1 = __builtin_amdgcn_mfma_f32_16x16x32_f16(a, b1, acc1, 0, 0, 0);
        acc2 = __builtin_amdgcn_mfma_f32_16x16x32_f16(a, b2, acc2, 0, 0, 0);
        acc3 = __builtin_amdgcn_mfma_f32_16x16x32_f16(a, b3, acc3, 0, 0, 0);
    }
#pragma unroll
    for (int reg = 0; reg < 4; ++reg) {
        int rr = r0 + wave * 16 + kg * 4 + reg;
        if (rr < N) {
            int col = lane & 15;
            size_t base = (size_t)rr * DHID;
            h1[base + col +  0] = __float2half(acc0[reg]);
            h1[base + col + 16] = __float2half(acc1[reg]);
            h1[base + col + 32] = __float2half(acc2[reg]);
            h1[base + col + 48] = __float2half(acc3[reg]);
        }
    }
}

// ------- K7: fused layer-1 aggregate + bias + ReLU + @W2 -----------
__global__ __launch_bounds__(256) void k_agg1(const __half* __restrict__ h1h,
                                              const int* __restrict__ rp,
                                              const int2* __restrict__ csw,
                                              const float* __restrict__ dinv,
                                              const float* __restrict__ b1,
                                              const float* __restrict__ W2,
                                              float* __restrict__ h2, int N) {
    int lane = threadIdx.x & 63;
    int i = (blockIdx.x * 256 + threadIdx.x) >> 6;
    if (i >= N) return;
    float bias = b1[lane];
    float w2a = W2[lane * 2];
    float w2b = W2[lane * 2 + 1];
    int s0 = __builtin_amdgcn_readfirstlane(rp[i]);
    int e0 = __builtin_amdgcn_readfirstlane(rp[i + 1]);
    float acc = 0.0f;
    int p = s0;
    for (; p + 8 <= e0; p += 8) {
        int2 eA = csw[p],     eB = csw[p + 1], eC = csw[p + 2], eD = csw[p + 3];
        int2 eE = csw[p + 4], eF = csw[p + 5], eG = csw[p + 6], eH = csw[p + 7];
        int sA = __builtin_amdgcn_readfirstlane(eA.x);
        int sB = __builtin_amdgcn_readfirstlane(eB.x);
        int sC = __builtin_amdgcn_readfirstlane(eC.x);
        int sD = __builtin_amdgcn_readfirstlane(eD.x);
        int sE = __builtin_amdgcn_readfirstlane(eE.x);
        int sF = __builtin_amdgcn_readfirstlane(eF.x);
        int sG = __builtin_amdgcn_readfirstlane(eG.x);
        int sH = __builtin_amdgcn_readfirstlane(eH.x);
        float wA = __uint_as_float(__builtin_amdgcn_readfirstlane(eA.y)) * dinv[sA];
        float wB = __uint_as_float(__builtin_amdgcn_readfirstlane(eB.y)) * dinv[sB];
        float wC = __uint_as_float(__builtin_amdgcn_readfirstlane(eC.y)) * dinv[sC];
        float wD = __uint_as_float(__builtin_amdgcn_readfirstlane(eD.y)) * dinv[sD];
        float wE = __uint_as_float(__builtin_amdgcn_readfirstlane(eE.y)) * dinv[sE];
        float wF = __uint_as_float(__builtin_amdgcn_readfirstlane(eF.y)) * dinv[sF];
        float wG = __uint_as_float(__builtin_amdgcn_readfirstlane(eG.y)) * dinv[sG];
        float wH = __uint_as_float(__builtin_amdgcn_readfirstlane(eH.y)) * dinv[sH];
        float hA = __half2float(h1h[(size_t)sA * DHID + lane]);
        float hB = __half2float(h1h[(size_t)sB * DHID + lane]);
        float hC = __half2float(h1h[(size_t)sC * DHID + lane]);
        float hD = __half2float(h1h[(size_t)sD * DHID + lane]);
        float hE = __half2float(h1h[(size_t)sE * DHID + lane]);
        float hF = __half2float(h1h[(size_t)sF * DHID + lane]);
        float hG = __half2float(h1h[(size_t)sG * DHID + lane]);
        float hH = __half2float(h1h[(size_t)sH * DHID + lane]);
        acc = fmaf(wA, hA, acc);
        acc = fmaf(wB, hB, acc);
        acc = fmaf(wC, hC, acc);
        acc = fmaf(wD, hD, acc);
        acc = fmaf(wE, hE, acc);
        acc = fmaf(wF, hF, acc);
        acc = fmaf(wG, hG, acc);
        acc = fmaf(wH, hH, acc);
    }
    for (; p + 4 <= e0; p += 4) {
        int2 eA = csw[p], eB = csw[p + 1], eC = csw[p + 2], eD = csw[p + 3];
        int sA = __builtin_amdgcn_readfirstlane(eA.x);
        int sB = __builtin_amdgcn_readfirstlane(eB.x);
        int sC = __builtin_amdgcn_readfirstlane(eC.x);
        int sD = __builtin_amdgcn_readfirstlane(eD.x);
        float wA = __uint_as_float(__builtin_amdgcn_readfirstlane(eA.y)) * dinv[sA];
        float wB = __uint_as_float(__builtin_amdgcn_readfirstlane(eB.y)) * dinv[sB];
        float wC = __uint_as_float(__builtin_amdgcn_readfirstlane(eC.y)) * dinv[sC];
        float wD = __uint_as_float(__builtin_amdgcn_readfirstlane(eD.y)) * dinv[sD];
        float hA = __half2float(h1h[(size_t)sA * DHID + lane]);
        float hB = __half2float(h1h[(size_t)sB * DHID + lane]);
        float hC = __half2float(h1h[(size_t)sC * DHID + lane]);
        float hD = __half2float(h1h[(size_t)sD * DHID + lane]);
        acc = fmaf(wA, hA, acc);
        acc = fmaf(wB, hB, acc);
        acc = fmaf(wC, hC, acc);
        acc = fmaf(wD, hD, acc);
    }
    for (; p < e0; ++p) {
        int2 eA = csw[p];
        int sA = __builtin_amdgcn_readfirstlane(eA.x);
        float wA = __uint_as_float(__builtin_amdgcn_readfirstlane(eA.y)) * dinv[sA];
        acc = fmaf(wA, __half2float(h1h[(size_t)sA * DHID + lane]), acc);
    }
    // self-loop + dst-side norm: di*(edge_sum + di*self)
    float di = dinv[i];
    acc = (acc + di * __half2float(h1h[(size_t)i * DHID + lane])) * di;
    acc = fmaxf(acc + bias, 0.0f);
    float o0 = acc * w2a, o1 = acc * w2b;
    for (int off = 32; off > 0; off >>= 1) {
        o0 += __shfl_xor(o0, off);
        o1 += __shfl_xor(o1, off);
    }
    if (lane == 0) {
        h2[i * 2]     = o0;
        h2[i * 2 + 1] = o1;
    }
}

// ------- K8: layer-2 propagate: out = di*(sum + di*self) + b2 ------
__global__ __launch_bounds__(256) void k_prop2(const float* __restrict__ h2,
                                               const int* __restrict__ rp,
                                               const int2* __restrict__ csw,
                                               const float* __restrict__ dinv,
                                               const float* __restrict__ b2,
                                               float* __restrict__ out, int N) {
    const float2* h2v = (const float2*)h2;
    int lane = threadIdx.x & 63;
    int i = (blockIdx.x * 256 + threadIdx.x) >> 6;
    if (i >= N) return;
    int s0 = rp[i], e0 = rp[i + 1];
    float a0 = 0.0f, a1 = 0.0f;
    for (int p = s0 + lane; p < e0; p += 64) {
        int2 ed = csw[p];
        float w = __int_as_float(ed.y) * dinv[ed.x];  // raw w * dinv[src]
        float2 hv = h2v[ed.x];
        a0 = fmaf(w, hv.x, a0);
        a1 = fmaf(w, hv.y, a1);
    }
    for (int off = 32; off > 0; off >>= 1) {
        a0 += __shfl_xor(a0, off);
        a1 += __shfl_xor(a1, off);
    }
    if (lane == 0) {
        float di = dinv[i];
        out[i * 2]     = di * (a0 + di * h2[i * 2])     + b2[0];
        out[i * 2 + 1] = di * (a1 + di * h2[i * 2 + 1]) + b2[1];
    }
}

extern "C" void kernel_launch(void* const* d_in, const int* in_sizes, int n_in,
                              void* d_out, int out_size, void* d_ws, size_t ws_size,
                              hipStream_t stream) {
    const float* x  = (const float*)d_in[0];
    const int*   ei = (const int*)d_in[1];     // int32 per harness contract
    const float* ew = (const float*)d_in[2];
    const float* W1 = (const float*)d_in[3];
    const float* b1 = (const float*)d_in[4];
    const float* W2 = (const float*)d_in[5];
    const float* b2 = (const float*)d_in[6];
    float* out = (float*)d_out;

    const int N = in_sizes[0] / DIN;   // 100000
    const int E = in_sizes[2];         // 3200000

    const int C = 256;                 // edge chunks (12.5K edges each)
    const int B = (N + 127) >> BSH;    // 782 buckets of 128 nodes
    const int chunk = (E + C - 1) / C;

    // workspace layout (~53 MB; ebuf aliased by h1/h2 after k_build)
    char* w0 = (char*)d_ws;
    float* dinv  = (float*)w0;                      // N floats
    int*   rp    = (int*)(dinv + N);                // N+1 ints (+3 pad)
    int*   histT = rp + (N + 4);                    // B*C ints (800 KB)
    int*   tot   = histT + (size_t)B * C;           // B ints
    int*   bb    = tot + B;                         // B+1 ints
    size_t off_csw = ((size_t)((char*)(bb + B + 1) - w0) + 15) & ~(size_t)15;
    int2*  csw  = (int2*)(w0 + off_csw);            // E pairs (25.6 MB)
    int2*  ebuf = csw + E;                          // E pairs (25.6 MB)
    __half* h1  = (__half*)ebuf;                    // alias: N*64 fp16 (12.8 MB)
    float* h2   = (float*)(h1 + (size_t)N * DHID);  // alias: N*2 fp32

    size_t ldsB = (size_t)B * sizeof(int);

    k_hist<<<C, 1024, ldsB, stream>>>(ei, histT, E, chunk, B, C);
    k_scan1<<<B, 256, 0, stream>>>(histT, tot, C);
    k_scan2<<<1, 1024, 0, stream>>>(tot, bb, B);
    k_scatter<<<C, 1024, 0, stream>>>(ei, ew, histT, bb, ebuf, E, chunk, B, C);
    k_build<<<B, 512, 0, stream>>>(ebuf, bb, rp, dinv, csw, N, E);

    const int GB = (N + 63) / 64;
    k_gemm1<<<GB, 256, 0, stream>>>(x, W1, h1, N);

    const int GW = ((size_t)N * 64 + 255) / 256;   // one wave per node
    k_agg1<<<GW, 256, 0, stream>>>(h1, rp, csw, dinv, b1, W2, h2, N);
    k_prop2<<<GW, 256, 0, stream>>>(h2, rp, csw, dinv, b2, out, N);
}